// Round 12
// baseline (730.299 us; speedup 1.0000x reference)
//
#include <hip/hip_runtime.h>

#define NN 100000
#define NE 200000
#define HH 32
#define NL 4
#define NGR 50
#define GOUT 100
#define NODE_IN 6
#define NEB 782  // ceil(NE/256)

typedef __attribute__((ext_vector_type(8))) short bf16x8;
typedef __attribute__((ext_vector_type(4))) float f32x4;

__device__ __forceinline__ unsigned short bf16_rne(float x) {
    unsigned int b = __float_as_uint(x);
    b += 0x7FFFu + ((b >> 16) & 1u);
    return (unsigned short)(b >> 16);
}
__device__ __forceinline__ float bf16_f(unsigned short h) {
    return __uint_as_float(((unsigned int)h) << 16);
}

// ---------------- w2 -> transposed bf16 hi/lo split: w2t[l][n][k] ----------------
__global__ __launch_bounds__(256) void split_w2(const float* __restrict__ w2,
                                                unsigned short* __restrict__ w2h,
                                                unsigned short* __restrict__ w2l)
{
    int id = blockIdx.x * 256 + threadIdx.x;
    if (id >= NL * 64 * 1024) return;
    int l = id >> 16, rem = id & 65535;
    int k = rem >> 10, n = rem & 1023;
    float v = w2[id];
    unsigned short hi = bf16_rne(v);
    float lov = v - bf16_f(hi);
    unsigned short lo = bf16_rne(lov);
    int out = l * 65536 + n * 64 + k;
    w2h[out] = hi;
    w2l[out] = lo;
}

// ---------------- embed: h0 = relu(x @ w_emb + b_emb) ----------------
__global__ __launch_bounds__(256) void embed_kernel(
    const float* __restrict__ x, const float* __restrict__ w,
    const float* __restrict__ b, float* __restrict__ h0)
{
    int nid = blockIdx.x * 256 + threadIdx.x;
    if (nid >= NN) return;
    float xv[NODE_IN];
    #pragma unroll
    for (int d = 0; d < NODE_IN; ++d) xv[d] = x[nid * NODE_IN + d];
    float4* op = (float4*)(h0 + (size_t)nid * HH);
    #pragma unroll
    for (int q = 0; q < 8; ++q) {
        float4 r;
        float* rp = (float*)&r;
        #pragma unroll
        for (int u = 0; u < 4; ++u) {
            int j = q * 4 + u;
            float a = b[j];
            #pragma unroll
            for (int d = 0; d < NODE_IN; ++d) a = fmaf(xv[d], w[d * HH + j], a);
            rp[u] = fmaxf(a, 0.f);
        }
        op[q] = r;
    }
}

// ---------------- BN stats ----------------
__global__ __launch_bounds__(256) void stats_kernel(const float* __restrict__ h0,
                                                    float* __restrict__ stats)
{
    __shared__ float ls[64];
    int tid = threadIdx.x;
    if (tid < 64) ls[tid] = 0.f;
    __syncthreads();
    float s[4] = {0.f, 0.f, 0.f, 0.f};
    float q[4] = {0.f, 0.f, 0.f, 0.f};
    const float4* h4 = (const float4*)h0;
    const int total = NN * HH / 4;
    for (int idx = blockIdx.x * 256 + tid; idx < total; idx += 128 * 256) {
        float4 v = h4[idx];
        s[0] += v.x; q[0] += v.x * v.x;
        s[1] += v.y; q[1] += v.y * v.y;
        s[2] += v.z; q[2] += v.z * v.z;
        s[3] += v.w; q[3] += v.w * v.w;
    }
    int c0 = (tid * 4) & 31;
    #pragma unroll
    for (int u = 0; u < 4; ++u) {
        atomicAdd(&ls[c0 + u], s[u]);
        atomicAdd(&ls[32 + c0 + u], q[u]);
    }
    __syncthreads();
    if (tid < 64) unsafeAtomicAdd(&stats[tid], ls[tid]);
}

// ---------------- int degree ----------------
__global__ __launch_bounds__(256) void degi_kernel(const int* __restrict__ ei,
                                                   int* __restrict__ degi)
{
    int e = blockIdx.x * 256 + threadIdx.x;
    if (e >= NE) return;
    atomicAdd(&degi[ei[NE + e]], 1);
}

__global__ void bn_finalize(const float* __restrict__ stats,
                            const float* __restrict__ gamma,
                            const float* __restrict__ beta,
                            float* __restrict__ bnp)
{
    int j = threadIdx.x;
    if (j >= HH) return;
    const float invn = 1.0f / (float)NN;
    float mu  = stats[j] * invn;
    float var = stats[32 + j] * invn - mu * mu;
    float rs  = 1.0f / sqrtf(var + 1e-5f);
    float sc  = rs * gamma[j];
    bnp[j]      = sc;
    bnp[32 + j] = beta[j] - mu * sc;
}

__global__ __launch_bounds__(256) void bn_apply(float* __restrict__ h,
                                                const float* __restrict__ bnp)
{
    int idx = blockIdx.x * 256 + threadIdx.x;
    if (idx >= NN * HH / 4) return;
    float4 v = ((float4*)h)[idx];
    int j = (idx * 4) & 31;
    v.x = fmaf(v.x, bnp[j + 0], bnp[32 + j + 0]);
    v.y = fmaf(v.y, bnp[j + 1], bnp[32 + j + 1]);
    v.z = fmaf(v.z, bnp[j + 2], bnp[32 + j + 2]);
    v.w = fmaf(v.w, bnp[j + 3], bnp[32 + j + 3]);
    ((float4*)h)[idx] = v;
}

// ---------------- CSR build: scan + scatter (dst order is layer-invariant) ----------
__global__ __launch_bounds__(256) void scan1(const int* __restrict__ degi,
                                             int* __restrict__ rowptr,
                                             int* __restrict__ bsum)
{
    __shared__ int sd[256];
    int tid = threadIdx.x;
    int i = blockIdx.x * 256 + tid;
    int v = (i < NN) ? degi[i] : 0;
    sd[tid] = v;
    __syncthreads();
    #pragma unroll
    for (int off = 1; off < 256; off <<= 1) {
        int t = (tid >= off) ? sd[tid - off] : 0;
        __syncthreads();
        sd[tid] += t;
        __syncthreads();
    }
    if (i < NN) rowptr[i] = sd[tid] - v;
    if (tid == 255) bsum[blockIdx.x] = sd[255];
}

__global__ __launch_bounds__(512) void scan2(int* __restrict__ bsum)
{
    __shared__ int sd[512];
    int tid = threadIdx.x;
    int v = (tid < 391) ? bsum[tid] : 0;
    sd[tid] = v;
    __syncthreads();
    #pragma unroll
    for (int off = 1; off < 512; off <<= 1) {
        int t = (tid >= off) ? sd[tid - off] : 0;
        __syncthreads();
        sd[tid] += t;
        __syncthreads();
    }
    if (tid < 391) bsum[tid] = sd[tid] - v;
}

__global__ __launch_bounds__(256) void scan3(int* __restrict__ rowptr,
                                             const int* __restrict__ bsum,
                                             int* __restrict__ cursor)
{
    int i = blockIdx.x * 256 + threadIdx.x;
    if (i < NN) {
        int r = rowptr[i] + bsum[blockIdx.x];
        rowptr[i] = r;
        cursor[i] = r;
    }
    if (i == 0) rowptr[NN] = NE;
}

__global__ __launch_bounds__(256) void scatter_k(const int* __restrict__ ei,
                                                 int* __restrict__ cursor,
                                                 int* __restrict__ perm)
{
    int e = blockIdx.x * 256 + threadIdx.x;
    if (e >= NE) return;
    int d = ei[NE + e];
    int pos = atomicAdd(&cursor[d], 1);
    perm[pos] = e;
}

// ---------------- NNConv edge kernel via MFMA; 8 waves x 32 edges (R7, proven) -----
// Best verified config: 64 VGPR, 53248 B LDS, 3 blk/CU, edge ~94us.
// Falsified alternates (do NOT reintroduce):
//  - __launch_bounds__(256,3)/(512,3): allocator spills acc to scratch (R4: 9x HBM).
//  - B direct-from-global ping-pong: request-rate bound, 165us (R6).
//  - memory-gathered acc init (b2h): 128-VGPR spill cliff (R8/R9).
//  - double-buffered staging (64-col or 32-col): compiler orders LDS-DMA vs ds_read
//    conservatively -> serializes worse than the barrier drain, 118-119us (R10/R11).
__global__ __launch_bounds__(512) void edge_mfma(
    const float* __restrict__ h, const int* __restrict__ ei,
    const float* __restrict__ ea, const int* __restrict__ perm,
    const float* __restrict__ w1, const float* __restrict__ b1,
    const unsigned short* __restrict__ w2h, const unsigned short* __restrict__ w2l,
    const float* __restrict__ b2, float* __restrict__ msg)
{
    __shared__ float hT[32 * 256];              // 32 KB
    __shared__ float b2l[1024];                 // 4 KB
    __shared__ unsigned short Bh[4096];         // 8 KB: 64 n-rows x 64 k, swizzled
    __shared__ unsigned short Bl[4096];         // 8 KB   (total 53248 B)

    const int tid  = threadIdx.x;
    const int w    = tid >> 6;                  // 0..7
    const int lane = tid & 63;
    const int l15  = lane & 15;
    const int lg   = lane >> 4;                 // 0..3
    const int eb   = blockIdx.x * 256;
    const int wb32 = w * 32;                    // wave's edge sub-tile base

    const unsigned int* gh = (const unsigned int*)w2h;   // granule = 16 B
    const unsigned int* gl = (const unsigned int*)w2l;

    auto stage = [&](int c2) {
        int n = tid >> 3, j = tid & 7;           // granule id = tid (512 total)
        int gi = ((c2 * 64 + n) << 3) + (j ^ (n & 7));
        int lb = (tid & ~63) * 8;                // shorts; wave-uniform base
        __builtin_amdgcn_global_load_lds(
            (const __attribute__((address_space(1))) unsigned int*)(gh + (size_t)gi * 4),
            (__attribute__((address_space(3))) unsigned int*)(&Bh[0] + lb), 16, 0, 0);
        __builtin_amdgcn_global_load_lds(
            (const __attribute__((address_space(1))) unsigned int*)(gl + (size_t)gi * 4),
            (__attribute__((address_space(3))) unsigned int*)(&Bl[0] + lb), 16, 0, 0);
    };

    // ---- stage per-block edge data (dst-sorted via perm); 2 threads per edge ----
    {
        int eloc = tid & 255;
        int half = tid >> 8;                     // 0 or 1 -> columns 0-15 / 16-31
        int e = eb + eloc;
        int pe = (e < NE) ? perm[e] : 0;
        int s  = (e < NE) ? ei[pe] : 0;
        const float4* hp = (const float4*)(h + (size_t)s * HH) + half * 4;
        #pragma unroll
        for (int q = 0; q < 4; ++q) {
            float4 v = hp[q];
            int col = half * 16 + q * 4;
            hT[(col + 0) * 256 + eloc] = v.x;
            hT[(col + 1) * 256 + eloc] = v.y;
            hT[(col + 2) * 256 + eloc] = v.z;
            hT[(col + 3) * 256 + eloc] = v.w;
        }
        if (tid < 256) ((float4*)b2l)[tid] = ((const float4*)b2)[tid];
    }

    // ---- A-operand fragments: T = relu(ea@w1+b1), split hi/lo bf16 (et = 0,1) ----
    bf16x8 thi[2][2], tlo[2][2];
    #pragma unroll
    for (int et = 0; et < 2; ++et) {
        int e2 = eb + wb32 + et * 16 + l15;
        bool ev = (e2 < NE);
        int pe2 = ev ? perm[e2] : 0;
        float4 eav = make_float4(0.f, 0.f, 0.f, 0.f);
        if (ev) eav = *(const float4*)(ea + (size_t)pe2 * 4);
        #pragma unroll
        for (int ks = 0; ks < 2; ++ks) {
            int k0 = ks * 32 + lg * 8;
            #pragma unroll
            for (int j = 0; j < 8; ++j) {
                float t = b1[k0 + j];
                t = fmaf(eav.x, w1[0 * 64 + k0 + j], t);
                t = fmaf(eav.y, w1[1 * 64 + k0 + j], t);
                t = fmaf(eav.z, w1[2 * 64 + k0 + j], t);
                t = fmaf(eav.w, w1[3 * 64 + k0 + j], t);
                t = ev ? fmaxf(t, 0.f) : 0.f;
                unsigned short hi = bf16_rne(t);
                float lov = t - bf16_f(hi);
                unsigned short lo = bf16_rne(lov);
                thi[et][ks][j] = (short)hi;
                tlo[et][ks][j] = (short)lo;
            }
        }
    }

    float acc0[2][4], acc1[2][4];
    #pragma unroll
    for (int et = 0; et < 2; ++et)
        #pragma unroll
        for (int r = 0; r < 4; ++r) { acc0[et][r] = 0.f; acc1[et][r] = 0.f; }

    // ---- main loop: 16 chunks of 64 n-cols, single LDS buffer ----
    for (int c2 = 0; c2 < 16; ++c2) {
        __syncthreads();                 // buffer reusable (covers hT staging at c2==0)
        stage(c2);
        __syncthreads();                 // vmcnt drained before barrier -> data visible

        #pragma unroll
        for (int ntp = 0; ntp < 2; ++ntp) {
            const int i = c2 * 2 + ntp;  // h row for this 32-col pair
            float4 h4[2];
            #pragma unroll
            for (int et = 0; et < 2; ++et)
                h4[et] = *(const float4*)&hT[i * 256 + wb32 + et * 16 + lg * 4];
            #pragma unroll
            for (int half = 0; half < 2; ++half) {
                int nt = ntp * 2 + half;           // 0..3 within chunk
                int nl = nt * 16 + l15;            // chunk-local n row
                int swz = (nl & 7) << 4;
                const char* bhrow = (const char*)&Bh[0] + nl * 128;
                const char* blrow = (const char*)&Bl[0] + nl * 128;
                bf16x8 Bh0 = *(const bf16x8*)(bhrow + (( 0 + lg * 16) ^ swz));
                bf16x8 Bl0 = *(const bf16x8*)(blrow + (( 0 + lg * 16) ^ swz));
                bf16x8 Bh1 = *(const bf16x8*)(bhrow + ((64 + lg * 16) ^ swz));
                bf16x8 Bl1 = *(const bf16x8*)(blrow + ((64 + lg * 16) ^ swz));
                float b2v = b2l[c2 * 64 + nt * 16 + l15];
                #pragma unroll
                for (int et = 0; et < 2; ++et) {
                    f32x4 G = {0.f, 0.f, 0.f, 0.f};
                    G = __builtin_amdgcn_mfma_f32_16x16x32_bf16(thi[et][0], Bh0, G, 0, 0, 0);
                    G = __builtin_amdgcn_mfma_f32_16x16x32_bf16(tlo[et][0], Bh0, G, 0, 0, 0);
                    G = __builtin_amdgcn_mfma_f32_16x16x32_bf16(thi[et][0], Bl0, G, 0, 0, 0);
                    G = __builtin_amdgcn_mfma_f32_16x16x32_bf16(thi[et][1], Bh1, G, 0, 0, 0);
                    G = __builtin_amdgcn_mfma_f32_16x16x32_bf16(tlo[et][1], Bh1, G, 0, 0, 0);
                    G = __builtin_amdgcn_mfma_f32_16x16x32_bf16(thi[et][1], Bl1, G, 0, 0, 0);
                    if (half == 0) {
                        acc0[et][0] = fmaf(h4[et].x, G[0] + b2v, acc0[et][0]);
                        acc0[et][1] = fmaf(h4[et].y, G[1] + b2v, acc0[et][1]);
                        acc0[et][2] = fmaf(h4[et].z, G[2] + b2v, acc0[et][2]);
                        acc0[et][3] = fmaf(h4[et].w, G[3] + b2v, acc0[et][3]);
                    } else {
                        acc1[et][0] = fmaf(h4[et].x, G[0] + b2v, acc1[et][0]);
                        acc1[et][1] = fmaf(h4[et].y, G[1] + b2v, acc1[et][1]);
                        acc1[et][2] = fmaf(h4[et].z, G[2] + b2v, acc1[et][2]);
                        acc1[et][3] = fmaf(h4[et].w, G[3] + b2v, acc1[et][3]);
                    }
                }
            }
        }
    }

    // ---- plain coalesced stores (msg indexed by sorted position) ----
    #pragma unroll
    for (int et = 0; et < 2; ++et) {
        #pragma unroll
        for (int r = 0; r < 4; ++r) {
            int row = eb + wb32 + et * 16 + lg * 4 + r;
            if (row < NE) {
                msg[(size_t)row * HH + l15]      = acc0[et][r];
                msg[(size_t)row * HH + 16 + l15] = acc1[et][r];
            }
        }
    }
}

// ---------------- node update: CSR gather (no atomics) ----------------
__global__ __launch_bounds__(256) void node_kernel(
    const float* __restrict__ h, const float* __restrict__ msg,
    const int* __restrict__ rowptr, const float* __restrict__ root,
    const float* __restrict__ bias, float* __restrict__ hout)
{
    int nid = blockIdx.x * 256 + threadIdx.x;
    if (nid >= NN) return;
    int j0 = rowptr[nid], j1 = rowptr[nid + 1];
    float hv[HH];
    {
        const float4* hp = (const float4*)(h + (size_t)nid * HH);
        #pragma unroll
        for (int q = 0; q < 8; ++q) {
            float4 v = hp[q];
            hv[4*q+0] = v.x; hv[4*q+1] = v.y; hv[4*q+2] = v.z; hv[4*q+3] = v.w;
        }
    }
    float acc[HH];
    #pragma unroll
    for (int o = 0; o < HH; ++o) acc[o] = bias[o];
    #pragma unroll
    for (int i = 0; i < HH; ++i) {
        float hi = hv[i];
        #pragma unroll
        for (int o = 0; o < HH; ++o) acc[o] = fmaf(hi, root[i * HH + o], acc[o]);
    }
    float s[HH];
    #pragma unroll
    for (int o = 0; o < HH; ++o) s[o] = 0.f;
    for (int j = j0; j < j1; ++j) {
        const float4* mp = (const float4*)(msg + (size_t)j * HH);
        #pragma unroll
        for (int q = 0; q < 8; ++q) {
            float4 m = mp[q];
            s[4*q+0] += m.x; s[4*q+1] += m.y; s[4*q+2] += m.z; s[4*q+3] += m.w;
        }
    }
    float inv = 1.0f / fmaxf((float)(j1 - j0), 1.0f);
    float4* op = (float4*)(hout + (size_t)nid * HH);
    #pragma unroll
    for (int q = 0; q < 8; ++q) {
        float4 r;
        r.x = fmaxf(fmaf(s[4*q+0], inv, acc[4*q+0]), 0.f);
        r.y = fmaxf(fmaf(s[4*q+1], inv, acc[4*q+1]), 0.f);
        r.z = fmaxf(fmaf(s[4*q+2], inv, acc[4*q+2]), 0.f);
        r.w = fmaxf(fmaf(s[4*q+3], inv, acc[4*q+3]), 0.f);
        op[q] = r;
    }
}

// ---------------- global mean pool (sorted batch -> run accumulation) ----------------
__global__ __launch_bounds__(256) void pool_kernel(
    const float* __restrict__ h, const int* __restrict__ batch,
    float* __restrict__ pool, float* __restrict__ cnt)
{
    __shared__ float lp[NGR * HH];
    __shared__ float lc[NGR];
    int tid = threadIdx.x;
    for (int i = tid; i < NGR * HH; i += 256) lp[i] = 0.f;
    if (tid < NGR) lc[tid] = 0.f;
    __syncthreads();
    int c = tid & 31, grp = tid >> 5;           // 8 groups x 32 cols
    int base = blockIdx.x * 1024 + grp * 128;
    int curg = -1;
    float acc = 0.f, cn = 0.f;
    for (int s = 0; s < 128; ++s) {
        int n = base + s;
        if (n >= NN) break;
        int g = batch[n];
        if (g != curg) {
            if (curg >= 0) {
                atomicAdd(&lp[curg * HH + c], acc);
                if (c == 0) atomicAdd(&lc[curg], cn);
            }
            curg = g; acc = 0.f; cn = 0.f;
        }
        acc += h[(size_t)n * HH + c];
        cn += 1.f;
    }
    if (curg >= 0) {
        atomicAdd(&lp[curg * HH + c], acc);
        if (c == 0) atomicAdd(&lc[curg], cn);
    }
    __syncthreads();
    for (int i = tid; i < NGR * HH; i += 256)
        if (lp[i] != 0.f) unsafeAtomicAdd(&pool[i], lp[i]);
    if (tid < NGR && lc[tid] != 0.f) unsafeAtomicAdd(&cnt[tid], lc[tid]);
}

// ---------------- heads ----------------
__global__ __launch_bounds__(256) void heads_kernel(
    const float* __restrict__ pool, const float* __restrict__ cnt,
    const float* __restrict__ wkw1, const float* __restrict__ wkb1,
    const float* __restrict__ wkw2, const float* __restrict__ wkb2,
    const float* __restrict__ ujw1, const float* __restrict__ ujb1,
    const float* __restrict__ ujw2, const float* __restrict__ ujb2,
    const float* __restrict__ zkw1, const float* __restrict__ zkb1,
    const float* __restrict__ zkw2, const float* __restrict__ zkb2,
    float* __restrict__ out)
{
    __shared__ float hg[NGR * HH];
    __shared__ float hid[NGR * HH];
    int tid = threadIdx.x;
    int head = blockIdx.x;
    const float *w1, *b1, *w2, *b2;
    if (head == 0)      { w1 = wkw1; b1 = wkb1; w2 = wkw2; b2 = wkb2; }
    else if (head == 1) { w1 = ujw1; b1 = ujb1; w2 = ujw2; b2 = ujb2; }
    else                { w1 = zkw1; b1 = zkb1; w2 = zkw2; b2 = zkb2; }
    for (int i = tid; i < NGR * HH; i += 256) {
        int g = i >> 5;
        hg[i] = pool[i] / fmaxf(cnt[g], 1.0f);
    }
    __syncthreads();
    for (int i = tid; i < NGR * HH; i += 256) {
        int g = i >> 5, c = i & 31;
        float a = b1[c];
        for (int j = 0; j < HH; ++j) a = fmaf(hg[g * HH + j], w1[j * HH + c], a);
        hid[i] = fmaxf(a, 0.f);
    }
    __syncthreads();
    if (head == 0) {
        if (tid < NGR) {
            float a = b2[0];
            for (int c = 0; c < HH; ++c) a = fmaf(hid[tid * HH + c], w2[c], a);
            out[tid] = a;
        }
    } else {
        float* ob = out + NGR + (head - 1) * NGR * GOUT;
        for (int i = tid; i < NGR * GOUT; i += 256) {
            int g = i / GOUT, u = i % GOUT;
            float a = b2[u];
            for (int c = 0; c < HH; ++c) a = fmaf(hid[g * HH + c], w2[c * GOUT + u], a);
            ob[i] = a;
        }
    }
}

extern "C" void kernel_launch(void* const* d_in, const int* in_sizes, int n_in,
                              void* d_out, int out_size, void* d_ws, size_t ws_size,
                              hipStream_t stream)
{
    const float* x     = (const float*)d_in[0];
    const int*   ei    = (const int*)d_in[1];
    const float* ea    = (const float*)d_in[2];
    const int*   batch = (const int*)d_in[3];
    const float* w_emb = (const float*)d_in[4];
    const float* b_emb = (const float*)d_in[5];
    const float* gamma = (const float*)d_in[6];
    const float* beta  = (const float*)d_in[7];
    const float* cw1   = (const float*)d_in[8];
    const float* cb1   = (const float*)d_in[9];
    const float* cw2   = (const float*)d_in[10];
    const float* cb2   = (const float*)d_in[11];
    const float* croot = (const float*)d_in[12];
    const float* cbias = (const float*)d_in[13];
    float* out = (float*)d_out;

    // ---- ws layout (16B-aligned chunks) ----
    unsigned short* w2h = (unsigned short*)d_ws;           // 512 KB
    unsigned short* w2l = w2h + 262144;                    // 512 KB
    float* msg    = (float*)(w2l + 262144);                // 25.6 MB
    float* h0     = msg + (size_t)NE * HH;                 // 12.8 MB
    float* h1     = h0 + (size_t)NN * HH;                  // 12.8 MB
    int*   rowptr = (int*)(h1 + (size_t)NN * HH);          // 100004
    int*   cursor = rowptr + 100004;                       // NN
    int*   perm   = cursor + NN;                           // NE
    int*   degi   = perm + NE;                             // NN   <- zero from here
    int*   bsum   = degi + NN;                             // 512
    float* stats  = (float*)(bsum + 512);                  // 64
    float* pool   = stats + 64;                            // 1600
    float* cnt    = pool + NGR * HH;                       // 50
    float* bnp    = cnt + NGR;                             // 64

    hipMemsetAsync(degi, 0, (size_t)(NN + 512 + 64 + NGR * HH + NGR) * sizeof(int), stream);

    split_w2<<<(NL * 65536) / 256, 256, 0, stream>>>(cw2, w2h, w2l);
    embed_kernel<<<(NN + 255) / 256, 256, 0, stream>>>(x, w_emb, b_emb, h0);
    stats_kernel<<<128, 256, 0, stream>>>(h0, stats);
    degi_kernel<<<NEB, 256, 0, stream>>>(ei, degi);
    bn_finalize<<<1, 32, 0, stream>>>(stats, gamma, beta, bnp);
    bn_apply<<<(NN * HH / 4 + 255) / 256, 256, 0, stream>>>(h0, bnp);

    // CSR build (dst order is layer-invariant)
    scan1<<<391, 256, 0, stream>>>(degi, rowptr, bsum);
    scan2<<<1, 512, 0, stream>>>(bsum);
    scan3<<<391, 256, 0, stream>>>(rowptr, bsum, cursor);
    scatter_k<<<NEB, 256, 0, stream>>>(ei, cursor, perm);

    float* hc = h0;
    float* hn = h1;
    for (int l = 0; l < NL; ++l) {
        edge_mfma<<<NEB, 512, 0, stream>>>(
            hc, ei, ea, perm,
            cw1 + (size_t)l * 4 * 64, cb1 + (size_t)l * 64,
            w2h + (size_t)l * 65536, w2l + (size_t)l * 65536,
            cb2 + (size_t)l * 1024, msg);
        node_kernel<<<(NN + 255) / 256, 256, 0, stream>>>(
            hc, msg, rowptr, croot + (size_t)l * HH * HH, cbias + (size_t)l * HH, hn);
        float* t = hc; hc = hn; hn = t;
    }

    pool_kernel<<<(NN + 1023) / 1024, 256, 0, stream>>>(hc, batch, pool, cnt);
    heads_kernel<<<3, 256, 0, stream>>>(pool, cnt,
        (const float*)d_in[14], (const float*)d_in[15], (const float*)d_in[16], (const float*)d_in[17],
        (const float*)d_in[18], (const float*)d_in[19], (const float*)d_in[20], (const float*)d_in[21],
        (const float*)d_in[22], (const float*)d_in[23], (const float*)d_in[24], (const float*)d_in[25],
        out);
}

// Round 13
// 727.708 us; speedup vs baseline: 1.0036x; 1.0036x over previous
//
#include <hip/hip_runtime.h>

#define NN 100000
#define NE 200000
#define HH 32
#define NL 4
#define NGR 50
#define GOUT 100
#define NODE_IN 6
#define NEB 782  // ceil(NE/256)

typedef __attribute__((ext_vector_type(8))) short bf16x8;
typedef __attribute__((ext_vector_type(4))) float f32x4;

__device__ __forceinline__ unsigned short bf16_rne(float x) {
    unsigned int b = __float_as_uint(x);
    b += 0x7FFFu + ((b >> 16) & 1u);
    return (unsigned short)(b >> 16);
}
__device__ __forceinline__ float bf16_f(unsigned short h) {
    return __uint_as_float(((unsigned int)h) << 16);
}

// ---------------- w2 -> transposed bf16 hi/lo split: w2t[l][n][k] ----------------
__global__ __launch_bounds__(256) void split_w2(const float* __restrict__ w2,
                                                unsigned short* __restrict__ w2h,
                                                unsigned short* __restrict__ w2l)
{
    int id = blockIdx.x * 256 + threadIdx.x;
    if (id >= NL * 64 * 1024) return;
    int l = id >> 16, rem = id & 65535;
    int k = rem >> 10, n = rem & 1023;
    float v = w2[id];
    unsigned short hi = bf16_rne(v);
    float lov = v - bf16_f(hi);
    unsigned short lo = bf16_rne(lov);
    int out = l * 65536 + n * 64 + k;
    w2h[out] = hi;
    w2l[out] = lo;
}

// ---------------- embed: h0 = relu(x @ w_emb + b_emb) ----------------
__global__ __launch_bounds__(256) void embed_kernel(
    const float* __restrict__ x, const float* __restrict__ w,
    const float* __restrict__ b, float* __restrict__ h0)
{
    int nid = blockIdx.x * 256 + threadIdx.x;
    if (nid >= NN) return;
    float xv[NODE_IN];
    #pragma unroll
    for (int d = 0; d < NODE_IN; ++d) xv[d] = x[nid * NODE_IN + d];
    float4* op = (float4*)(h0 + (size_t)nid * HH);
    #pragma unroll
    for (int q = 0; q < 8; ++q) {
        float4 r;
        float* rp = (float*)&r;
        #pragma unroll
        for (int u = 0; u < 4; ++u) {
            int j = q * 4 + u;
            float a = b[j];
            #pragma unroll
            for (int d = 0; d < NODE_IN; ++d) a = fmaf(xv[d], w[d * HH + j], a);
            rp[u] = fmaxf(a, 0.f);
        }
        op[q] = r;
    }
}

// ---------------- BN stats ----------------
__global__ __launch_bounds__(256) void stats_kernel(const float* __restrict__ h0,
                                                    float* __restrict__ stats)
{
    __shared__ float ls[64];
    int tid = threadIdx.x;
    if (tid < 64) ls[tid] = 0.f;
    __syncthreads();
    float s[4] = {0.f, 0.f, 0.f, 0.f};
    float q[4] = {0.f, 0.f, 0.f, 0.f};
    const float4* h4 = (const float4*)h0;
    const int total = NN * HH / 4;
    for (int idx = blockIdx.x * 256 + tid; idx < total; idx += 128 * 256) {
        float4 v = h4[idx];
        s[0] += v.x; q[0] += v.x * v.x;
        s[1] += v.y; q[1] += v.y * v.y;
        s[2] += v.z; q[2] += v.z * v.z;
        s[3] += v.w; q[3] += v.w * v.w;
    }
    int c0 = (tid * 4) & 31;
    #pragma unroll
    for (int u = 0; u < 4; ++u) {
        atomicAdd(&ls[c0 + u], s[u]);
        atomicAdd(&ls[32 + c0 + u], q[u]);
    }
    __syncthreads();
    if (tid < 64) unsafeAtomicAdd(&stats[tid], ls[tid]);
}

// ---------------- int degree ----------------
__global__ __launch_bounds__(256) void degi_kernel(const int* __restrict__ ei,
                                                   int* __restrict__ degi)
{
    int e = blockIdx.x * 256 + threadIdx.x;
    if (e >= NE) return;
    atomicAdd(&degi[ei[NE + e]], 1);
}

__global__ void bn_finalize(const float* __restrict__ stats,
                            const float* __restrict__ gamma,
                            const float* __restrict__ beta,
                            float* __restrict__ bnp)
{
    int j = threadIdx.x;
    if (j >= HH) return;
    const float invn = 1.0f / (float)NN;
    float mu  = stats[j] * invn;
    float var = stats[32 + j] * invn - mu * mu;
    float rs  = 1.0f / sqrtf(var + 1e-5f);
    float sc  = rs * gamma[j];
    bnp[j]      = sc;
    bnp[32 + j] = beta[j] - mu * sc;
}

__global__ __launch_bounds__(256) void bn_apply(float* __restrict__ h,
                                                const float* __restrict__ bnp)
{
    int idx = blockIdx.x * 256 + threadIdx.x;
    if (idx >= NN * HH / 4) return;
    float4 v = ((float4*)h)[idx];
    int j = (idx * 4) & 31;
    v.x = fmaf(v.x, bnp[j + 0], bnp[32 + j + 0]);
    v.y = fmaf(v.y, bnp[j + 1], bnp[32 + j + 1]);
    v.z = fmaf(v.z, bnp[j + 2], bnp[32 + j + 2]);
    v.w = fmaf(v.w, bnp[j + 3], bnp[32 + j + 3]);
    ((float4*)h)[idx] = v;
}

// ---------------- CSR build: scan + scatter (dst order is layer-invariant) ----------
__global__ __launch_bounds__(256) void scan1(const int* __restrict__ degi,
                                             int* __restrict__ rowptr,
                                             int* __restrict__ bsum)
{
    __shared__ int sd[256];
    int tid = threadIdx.x;
    int i = blockIdx.x * 256 + tid;
    int v = (i < NN) ? degi[i] : 0;
    sd[tid] = v;
    __syncthreads();
    #pragma unroll
    for (int off = 1; off < 256; off <<= 1) {
        int t = (tid >= off) ? sd[tid - off] : 0;
        __syncthreads();
        sd[tid] += t;
        __syncthreads();
    }
    if (i < NN) rowptr[i] = sd[tid] - v;
    if (tid == 255) bsum[blockIdx.x] = sd[255];
}

__global__ __launch_bounds__(512) void scan2(int* __restrict__ bsum)
{
    __shared__ int sd[512];
    int tid = threadIdx.x;
    int v = (tid < 391) ? bsum[tid] : 0;
    sd[tid] = v;
    __syncthreads();
    #pragma unroll
    for (int off = 1; off < 512; off <<= 1) {
        int t = (tid >= off) ? sd[tid - off] : 0;
        __syncthreads();
        sd[tid] += t;
        __syncthreads();
    }
    if (tid < 391) bsum[tid] = sd[tid] - v;
}

__global__ __launch_bounds__(256) void scan3(int* __restrict__ rowptr,
                                             const int* __restrict__ bsum,
                                             int* __restrict__ cursor)
{
    int i = blockIdx.x * 256 + threadIdx.x;
    if (i < NN) {
        int r = rowptr[i] + bsum[blockIdx.x];
        rowptr[i] = r;
        cursor[i] = r;
    }
    if (i == 0) rowptr[NN] = NE;
}

__global__ __launch_bounds__(256) void scatter_k(const int* __restrict__ ei,
                                                 int* __restrict__ cursor,
                                                 int* __restrict__ perm)
{
    int e = blockIdx.x * 256 + threadIdx.x;
    if (e >= NE) return;
    int d = ei[NE + e];
    int pos = atomicAdd(&cursor[d], 1);
    perm[pos] = e;
}

// ---------------- NNConv edge kernel via MFMA; 8 waves x 32 edges (R7, proven) -----
// Best verified config: 64-68 VGPR, 53248 B LDS, 3 blk/CU. R7 run: edge 94us/29.6%
// occ; R12 run of IDENTICAL source: 121us/17.4% occ + a bogus 30ms node dispatch ->
// cross-run machine variance, resubmitted verbatim to identify the stable mode.
// Falsified alternates (do NOT reintroduce):
//  - __launch_bounds__(256,3)/(512,3): allocator spills acc to scratch (R4: 9x HBM).
//  - B direct-from-global ping-pong: request-rate bound, 165us (R6).
//  - memory-gathered acc init (b2h): 128-VGPR spill cliff (R8/R9).
//  - double-buffered staging (64/32-col): LDS-DMA vs ds_read ordering serializes,
//    118-119us (R10/R11).
__global__ __launch_bounds__(512) void edge_mfma(
    const float* __restrict__ h, const int* __restrict__ ei,
    const float* __restrict__ ea, const int* __restrict__ perm,
    const float* __restrict__ w1, const float* __restrict__ b1,
    const unsigned short* __restrict__ w2h, const unsigned short* __restrict__ w2l,
    const float* __restrict__ b2, float* __restrict__ msg)
{
    __shared__ float hT[32 * 256];              // 32 KB
    __shared__ float b2l[1024];                 // 4 KB
    __shared__ unsigned short Bh[4096];         // 8 KB: 64 n-rows x 64 k, swizzled
    __shared__ unsigned short Bl[4096];         // 8 KB   (total 53248 B)

    const int tid  = threadIdx.x;
    const int w    = tid >> 6;                  // 0..7
    const int lane = tid & 63;
    const int l15  = lane & 15;
    const int lg   = lane >> 4;                 // 0..3
    const int eb   = blockIdx.x * 256;
    const int wb32 = w * 32;                    // wave's edge sub-tile base

    const unsigned int* gh = (const unsigned int*)w2h;   // granule = 16 B
    const unsigned int* gl = (const unsigned int*)w2l;

    auto stage = [&](int c2) {
        int n = tid >> 3, j = tid & 7;           // granule id = tid (512 total)
        int gi = ((c2 * 64 + n) << 3) + (j ^ (n & 7));
        int lb = (tid & ~63) * 8;                // shorts; wave-uniform base
        __builtin_amdgcn_global_load_lds(
            (const __attribute__((address_space(1))) unsigned int*)(gh + (size_t)gi * 4),
            (__attribute__((address_space(3))) unsigned int*)(&Bh[0] + lb), 16, 0, 0);
        __builtin_amdgcn_global_load_lds(
            (const __attribute__((address_space(1))) unsigned int*)(gl + (size_t)gi * 4),
            (__attribute__((address_space(3))) unsigned int*)(&Bl[0] + lb), 16, 0, 0);
    };

    // ---- stage per-block edge data (dst-sorted via perm); 2 threads per edge ----
    {
        int eloc = tid & 255;
        int half = tid >> 8;                     // 0 or 1 -> columns 0-15 / 16-31
        int e = eb + eloc;
        int pe = (e < NE) ? perm[e] : 0;
        int s  = (e < NE) ? ei[pe] : 0;
        const float4* hp = (const float4*)(h + (size_t)s * HH) + half * 4;
        #pragma unroll
        for (int q = 0; q < 4; ++q) {
            float4 v = hp[q];
            int col = half * 16 + q * 4;
            hT[(col + 0) * 256 + eloc] = v.x;
            hT[(col + 1) * 256 + eloc] = v.y;
            hT[(col + 2) * 256 + eloc] = v.z;
            hT[(col + 3) * 256 + eloc] = v.w;
        }
        if (tid < 256) ((float4*)b2l)[tid] = ((const float4*)b2)[tid];
    }

    // ---- A-operand fragments: T = relu(ea@w1+b1), split hi/lo bf16 (et = 0,1) ----
    bf16x8 thi[2][2], tlo[2][2];
    #pragma unroll
    for (int et = 0; et < 2; ++et) {
        int e2 = eb + wb32 + et * 16 + l15;
        bool ev = (e2 < NE);
        int pe2 = ev ? perm[e2] : 0;
        float4 eav = make_float4(0.f, 0.f, 0.f, 0.f);
        if (ev) eav = *(const float4*)(ea + (size_t)pe2 * 4);
        #pragma unroll
        for (int ks = 0; ks < 2; ++ks) {
            int k0 = ks * 32 + lg * 8;
            #pragma unroll
            for (int j = 0; j < 8; ++j) {
                float t = b1[k0 + j];
                t = fmaf(eav.x, w1[0 * 64 + k0 + j], t);
                t = fmaf(eav.y, w1[1 * 64 + k0 + j], t);
                t = fmaf(eav.z, w1[2 * 64 + k0 + j], t);
                t = fmaf(eav.w, w1[3 * 64 + k0 + j], t);
                t = ev ? fmaxf(t, 0.f) : 0.f;
                unsigned short hi = bf16_rne(t);
                float lov = t - bf16_f(hi);
                unsigned short lo = bf16_rne(lov);
                thi[et][ks][j] = (short)hi;
                tlo[et][ks][j] = (short)lo;
            }
        }
    }

    float acc0[2][4], acc1[2][4];
    #pragma unroll
    for (int et = 0; et < 2; ++et)
        #pragma unroll
        for (int r = 0; r < 4; ++r) { acc0[et][r] = 0.f; acc1[et][r] = 0.f; }

    // ---- main loop: 16 chunks of 64 n-cols, single LDS buffer ----
    for (int c2 = 0; c2 < 16; ++c2) {
        __syncthreads();                 // buffer reusable (covers hT staging at c2==0)
        stage(c2);
        __syncthreads();                 // vmcnt drained before barrier -> data visible

        #pragma unroll
        for (int ntp = 0; ntp < 2; ++ntp) {
            const int i = c2 * 2 + ntp;  // h row for this 32-col pair
            float4 h4[2];
            #pragma unroll
            for (int et = 0; et < 2; ++et)
                h4[et] = *(const float4*)&hT[i * 256 + wb32 + et * 16 + lg * 4];
            #pragma unroll
            for (int half = 0; half < 2; ++half) {
                int nt = ntp * 2 + half;           // 0..3 within chunk
                int nl = nt * 16 + l15;            // chunk-local n row
                int swz = (nl & 7) << 4;
                const char* bhrow = (const char*)&Bh[0] + nl * 128;
                const char* blrow = (const char*)&Bl[0] + nl * 128;
                bf16x8 Bh0 = *(const bf16x8*)(bhrow + (( 0 + lg * 16) ^ swz));
                bf16x8 Bl0 = *(const bf16x8*)(blrow + (( 0 + lg * 16) ^ swz));
                bf16x8 Bh1 = *(const bf16x8*)(bhrow + ((64 + lg * 16) ^ swz));
                bf16x8 Bl1 = *(const bf16x8*)(blrow + ((64 + lg * 16) ^ swz));
                float b2v = b2l[c2 * 64 + nt * 16 + l15];
                #pragma unroll
                for (int et = 0; et < 2; ++et) {
                    f32x4 G = {0.f, 0.f, 0.f, 0.f};
                    G = __builtin_amdgcn_mfma_f32_16x16x32_bf16(thi[et][0], Bh0, G, 0, 0, 0);
                    G = __builtin_amdgcn_mfma_f32_16x16x32_bf16(tlo[et][0], Bh0, G, 0, 0, 0);
                    G = __builtin_amdgcn_mfma_f32_16x16x32_bf16(thi[et][0], Bl0, G, 0, 0, 0);
                    G = __builtin_amdgcn_mfma_f32_16x16x32_bf16(thi[et][1], Bh1, G, 0, 0, 0);
                    G = __builtin_amdgcn_mfma_f32_16x16x32_bf16(tlo[et][1], Bh1, G, 0, 0, 0);
                    G = __builtin_amdgcn_mfma_f32_16x16x32_bf16(thi[et][1], Bl1, G, 0, 0, 0);
                    if (half == 0) {
                        acc0[et][0] = fmaf(h4[et].x, G[0] + b2v, acc0[et][0]);
                        acc0[et][1] = fmaf(h4[et].y, G[1] + b2v, acc0[et][1]);
                        acc0[et][2] = fmaf(h4[et].z, G[2] + b2v, acc0[et][2]);
                        acc0[et][3] = fmaf(h4[et].w, G[3] + b2v, acc0[et][3]);
                    } else {
                        acc1[et][0] = fmaf(h4[et].x, G[0] + b2v, acc1[et][0]);
                        acc1[et][1] = fmaf(h4[et].y, G[1] + b2v, acc1[et][1]);
                        acc1[et][2] = fmaf(h4[et].z, G[2] + b2v, acc1[et][2]);
                        acc1[et][3] = fmaf(h4[et].w, G[3] + b2v, acc1[et][3]);
                    }
                }
            }
        }
    }

    // ---- plain coalesced stores (msg indexed by sorted position) ----
    #pragma unroll
    for (int et = 0; et < 2; ++et) {
        #pragma unroll
        for (int r = 0; r < 4; ++r) {
            int row = eb + wb32 + et * 16 + lg * 4 + r;
            if (row < NE) {
                msg[(size_t)row * HH + l15]      = acc0[et][r];
                msg[(size_t)row * HH + 16 + l15] = acc1[et][r];
            }
        }
    }
}

// ---------------- node update: CSR gather (no atomics) ----------------
__global__ __launch_bounds__(256) void node_kernel(
    const float* __restrict__ h, const float* __restrict__ msg,
    const int* __restrict__ rowptr, const float* __restrict__ root,
    const float* __restrict__ bias, float* __restrict__ hout)
{
    int nid = blockIdx.x * 256 + threadIdx.x;
    if (nid >= NN) return;
    int j0 = rowptr[nid], j1 = rowptr[nid + 1];
    float hv[HH];
    {
        const float4* hp = (const float4*)(h + (size_t)nid * HH);
        #pragma unroll
        for (int q = 0; q < 8; ++q) {
            float4 v = hp[q];
            hv[4*q+0] = v.x; hv[4*q+1] = v.y; hv[4*q+2] = v.z; hv[4*q+3] = v.w;
        }
    }
    float acc[HH];
    #pragma unroll
    for (int o = 0; o < HH; ++o) acc[o] = bias[o];
    #pragma unroll
    for (int i = 0; i < HH; ++i) {
        float hi = hv[i];
        #pragma unroll
        for (int o = 0; o < HH; ++o) acc[o] = fmaf(hi, root[i * HH + o], acc[o]);
    }
    float s[HH];
    #pragma unroll
    for (int o = 0; o < HH; ++o) s[o] = 0.f;
    for (int j = j0; j < j1; ++j) {
        const float4* mp = (const float4*)(msg + (size_t)j * HH);
        #pragma unroll
        for (int q = 0; q < 8; ++q) {
            float4 m = mp[q];
            s[4*q+0] += m.x; s[4*q+1] += m.y; s[4*q+2] += m.z; s[4*q+3] += m.w;
        }
    }
    float inv = 1.0f / fmaxf((float)(j1 - j0), 1.0f);
    float4* op = (float4*)(hout + (size_t)nid * HH);
    #pragma unroll
    for (int q = 0; q < 8; ++q) {
        float4 r;
        r.x = fmaxf(fmaf(s[4*q+0], inv, acc[4*q+0]), 0.f);
        r.y = fmaxf(fmaf(s[4*q+1], inv, acc[4*q+1]), 0.f);
        r.z = fmaxf(fmaf(s[4*q+2], inv, acc[4*q+2]), 0.f);
        r.w = fmaxf(fmaf(s[4*q+3], inv, acc[4*q+3]), 0.f);
        op[q] = r;
    }
}

// ---------------- global mean pool (sorted batch -> run accumulation) ----------------
__global__ __launch_bounds__(256) void pool_kernel(
    const float* __restrict__ h, const int* __restrict__ batch,
    float* __restrict__ pool, float* __restrict__ cnt)
{
    __shared__ float lp[NGR * HH];
    __shared__ float lc[NGR];
    int tid = threadIdx.x;
    for (int i = tid; i < NGR * HH; i += 256) lp[i] = 0.f;
    if (tid < NGR) lc[tid] = 0.f;
    __syncthreads();
    int c = tid & 31, grp = tid >> 5;           // 8 groups x 32 cols
    int base = blockIdx.x * 1024 + grp * 128;
    int curg = -1;
    float acc = 0.f, cn = 0.f;
    for (int s = 0; s < 128; ++s) {
        int n = base + s;
        if (n >= NN) break;
        int g = batch[n];
        if (g != curg) {
            if (curg >= 0) {
                atomicAdd(&lp[curg * HH + c], acc);
                if (c == 0) atomicAdd(&lc[curg], cn);
            }
            curg = g; acc = 0.f; cn = 0.f;
        }
        acc += h[(size_t)n * HH + c];
        cn += 1.f;
    }
    if (curg >= 0) {
        atomicAdd(&lp[curg * HH + c], acc);
        if (c == 0) atomicAdd(&lc[curg], cn);
    }
    __syncthreads();
    for (int i = tid; i < NGR * HH; i += 256)
        if (lp[i] != 0.f) unsafeAtomicAdd(&pool[i], lp[i]);
    if (tid < NGR && lc[tid] != 0.f) unsafeAtomicAdd(&cnt[tid], lc[tid]);
}

// ---------------- heads ----------------
__global__ __launch_bounds__(256) void heads_kernel(
    const float* __restrict__ pool, const float* __restrict__ cnt,
    const float* __restrict__ wkw1, const float* __restrict__ wkb1,
    const float* __restrict__ wkw2, const float* __restrict__ wkb2,
    const float* __restrict__ ujw1, const float* __restrict__ ujb1,
    const float* __restrict__ ujw2, const float* __restrict__ ujb2,
    const float* __restrict__ zkw1, const float* __restrict__ zkb1,
    const float* __restrict__ zkw2, const float* __restrict__ zkb2,
    float* __restrict__ out)
{
    __shared__ float hg[NGR * HH];
    __shared__ float hid[NGR * HH];
    int tid = threadIdx.x;
    int head = blockIdx.x;
    const float *w1, *b1, *w2, *b2;
    if (head == 0)      { w1 = wkw1; b1 = wkb1; w2 = wkw2; b2 = wkb2; }
    else if (head == 1) { w1 = ujw1; b1 = ujb1; w2 = ujw2; b2 = ujb2; }
    else                { w1 = zkw1; b1 = zkb1; w2 = zkw2; b2 = zkb2; }
    for (int i = tid; i < NGR * HH; i += 256) {
        int g = i >> 5;
        hg[i] = pool[i] / fmaxf(cnt[g], 1.0f);
    }
    __syncthreads();
    for (int i = tid; i < NGR * HH; i += 256) {
        int g = i >> 5, c = i & 31;
        float a = b1[c];
        for (int j = 0; j < HH; ++j) a = fmaf(hg[g * HH + j], w1[j * HH + c], a);
        hid[i] = fmaxf(a, 0.f);
    }
    __syncthreads();
    if (head == 0) {
        if (tid < NGR) {
            float a = b2[0];
            for (int c = 0; c < HH; ++c) a = fmaf(hid[tid * HH + c], w2[c], a);
            out[tid] = a;
        }
    } else {
        float* ob = out + NGR + (head - 1) * NGR * GOUT;
        for (int i = tid; i < NGR * GOUT; i += 256) {
            int g = i / GOUT, u = i % GOUT;
            float a = b2[u];
            for (int c = 0; c < HH; ++c) a = fmaf(hid[g * HH + c], w2[c * GOUT + u], a);
            ob[i] = a;
        }
    }
}

extern "C" void kernel_launch(void* const* d_in, const int* in_sizes, int n_in,
                              void* d_out, int out_size, void* d_ws, size_t ws_size,
                              hipStream_t stream)
{
    const float* x     = (const float*)d_in[0];
    const int*   ei    = (const int*)d_in[1];
    const float* ea    = (const float*)d_in[2];
    const int*   batch = (const int*)d_in[3];
    const float* w_emb = (const float*)d_in[4];
    const float* b_emb = (const float*)d_in[5];
    const float* gamma = (const float*)d_in[6];
    const float* beta  = (const float*)d_in[7];
    const float* cw1   = (const float*)d_in[8];
    const float* cb1   = (const float*)d_in[9];
    const float* cw2   = (const float*)d_in[10];
    const float* cb2   = (const float*)d_in[11];
    const float* croot = (const float*)d_in[12];
    const float* cbias = (const float*)d_in[13];
    float* out = (float*)d_out;

    // ---- ws layout (16B-aligned chunks) ----
    unsigned short* w2h = (unsigned short*)d_ws;           // 512 KB
    unsigned short* w2l = w2h + 262144;                    // 512 KB
    float* msg    = (float*)(w2l + 262144);                // 25.6 MB
    float* h0     = msg + (size_t)NE * HH;                 // 12.8 MB
    float* h1     = h0 + (size_t)NN * HH;                  // 12.8 MB
    int*   rowptr = (int*)(h1 + (size_t)NN * HH);          // 100004
    int*   cursor = rowptr + 100004;                       // NN
    int*   perm   = cursor + NN;                           // NE
    int*   degi   = perm + NE;                             // NN   <- zero from here
    int*   bsum   = degi + NN;                             // 512
    float* stats  = (float*)(bsum + 512);                  // 64
    float* pool   = stats + 64;                            // 1600
    float* cnt    = pool + NGR * HH;                       // 50
    float* bnp    = cnt + NGR;                             // 64

    hipMemsetAsync(degi, 0, (size_t)(NN + 512 + 64 + NGR * HH + NGR) * sizeof(int), stream);

    split_w2<<<(NL * 65536) / 256, 256, 0, stream>>>(cw2, w2h, w2l);
    embed_kernel<<<(NN + 255) / 256, 256, 0, stream>>>(x, w_emb, b_emb, h0);
    stats_kernel<<<128, 256, 0, stream>>>(h0, stats);
    degi_kernel<<<NEB, 256, 0, stream>>>(ei, degi);
    bn_finalize<<<1, 32, 0, stream>>>(stats, gamma, beta, bnp);
    bn_apply<<<(NN * HH / 4 + 255) / 256, 256, 0, stream>>>(h0, bnp);

    // CSR build (dst order is layer-invariant)
    scan1<<<391, 256, 0, stream>>>(degi, rowptr, bsum);
    scan2<<<1, 512, 0, stream>>>(bsum);
    scan3<<<391, 256, 0, stream>>>(rowptr, bsum, cursor);
    scatter_k<<<NEB, 256, 0, stream>>>(ei, cursor, perm);

    float* hc = h0;
    float* hn = h1;
    for (int l = 0; l < NL; ++l) {
        edge_mfma<<<NEB, 512, 0, stream>>>(
            hc, ei, ea, perm,
            cw1 + (size_t)l * 4 * 64, cb1 + (size_t)l * 64,
            w2h + (size_t)l * 65536, w2l + (size_t)l * 65536,
            cb2 + (size_t)l * 1024, msg);
        node_kernel<<<(NN + 255) / 256, 256, 0, stream>>>(
            hc, msg, rowptr, croot + (size_t)l * HH * HH, cbias + (size_t)l * HH, hn);
        float* t = hc; hc = hn; hn = t;
    }

    pool_kernel<<<(NN + 1023) / 1024, 256, 0, stream>>>(hc, batch, pool, cnt);
    heads_kernel<<<3, 256, 0, stream>>>(pool, cnt,
        (const float*)d_in[14], (const float*)d_in[15], (const float*)d_in[16], (const float*)d_in[17],
        (const float*)d_in[18], (const float*)d_in[19], (const float*)d_in[20], (const float*)d_in[21],
        (const float*)d_in[22], (const float*)d_in[23], (const float*)d_in[24], (const float*)d_in[25],
        out);
}

// Round 14
// 618.368 us; speedup vs baseline: 1.1810x; 1.1768x over previous
//
#include <hip/hip_runtime.h>

#define NN 100000
#define NE 200000
#define HH 32
#define NL 4
#define NGR 50
#define GOUT 100
#define NODE_IN 6
#define NEB 782  // ceil(NE/256)

typedef __attribute__((ext_vector_type(8))) short bf16x8;
typedef __attribute__((ext_vector_type(4))) float f32x4;

__device__ __forceinline__ unsigned short bf16_rne(float x) {
    unsigned int b = __float_as_uint(x);
    b += 0x7FFFu + ((b >> 16) & 1u);
    return (unsigned short)(b >> 16);
}
__device__ __forceinline__ float bf16_f(unsigned short h) {
    return __uint_as_float(((unsigned int)h) << 16);
}

// ---------------- w2 -> transposed bf16 hi/lo split: w2t[l][n][k] ----------------
__global__ __launch_bounds__(256) void split_w2(const float* __restrict__ w2,
                                                unsigned short* __restrict__ w2h,
                                                unsigned short* __restrict__ w2l)
{
    int id = blockIdx.x * 256 + threadIdx.x;
    if (id >= NL * 64 * 1024) return;
    int l = id >> 16, rem = id & 65535;
    int k = rem >> 10, n = rem & 1023;
    float v = w2[id];
    unsigned short hi = bf16_rne(v);
    float lov = v - bf16_f(hi);
    unsigned short lo = bf16_rne(lov);
    int out = l * 65536 + n * 64 + k;
    w2h[out] = hi;
    w2l[out] = lo;
}

// ---------------- embed: h0 = relu(x @ w_emb + b_emb) ----------------
__global__ __launch_bounds__(256) void embed_kernel(
    const float* __restrict__ x, const float* __restrict__ w,
    const float* __restrict__ b, float* __restrict__ h0)
{
    int nid = blockIdx.x * 256 + threadIdx.x;
    if (nid >= NN) return;
    float xv[NODE_IN];
    #pragma unroll
    for (int d = 0; d < NODE_IN; ++d) xv[d] = x[nid * NODE_IN + d];
    float4* op = (float4*)(h0 + (size_t)nid * HH);
    #pragma unroll
    for (int q = 0; q < 8; ++q) {
        float4 r;
        float* rp = (float*)&r;
        #pragma unroll
        for (int u = 0; u < 4; ++u) {
            int j = q * 4 + u;
            float a = b[j];
            #pragma unroll
            for (int d = 0; d < NODE_IN; ++d) a = fmaf(xv[d], w[d * HH + j], a);
            rp[u] = fmaxf(a, 0.f);
        }
        op[q] = r;
    }
}

// ---------------- BN stats ----------------
__global__ __launch_bounds__(256) void stats_kernel(const float* __restrict__ h0,
                                                    float* __restrict__ stats)
{
    __shared__ float ls[64];
    int tid = threadIdx.x;
    if (tid < 64) ls[tid] = 0.f;
    __syncthreads();
    float s[4] = {0.f, 0.f, 0.f, 0.f};
    float q[4] = {0.f, 0.f, 0.f, 0.f};
    const float4* h4 = (const float4*)h0;
    const int total = NN * HH / 4;
    for (int idx = blockIdx.x * 256 + tid; idx < total; idx += 128 * 256) {
        float4 v = h4[idx];
        s[0] += v.x; q[0] += v.x * v.x;
        s[1] += v.y; q[1] += v.y * v.y;
        s[2] += v.z; q[2] += v.z * v.z;
        s[3] += v.w; q[3] += v.w * v.w;
    }
    int c0 = (tid * 4) & 31;
    #pragma unroll
    for (int u = 0; u < 4; ++u) {
        atomicAdd(&ls[c0 + u], s[u]);
        atomicAdd(&ls[32 + c0 + u], q[u]);
    }
    __syncthreads();
    if (tid < 64) unsafeAtomicAdd(&stats[tid], ls[tid]);
}

// ---------------- int degree ----------------
__global__ __launch_bounds__(256) void degi_kernel(const int* __restrict__ ei,
                                                   int* __restrict__ degi)
{
    int e = blockIdx.x * 256 + threadIdx.x;
    if (e >= NE) return;
    atomicAdd(&degi[ei[NE + e]], 1);
}

__global__ void bn_finalize(const float* __restrict__ stats,
                            const float* __restrict__ gamma,
                            const float* __restrict__ beta,
                            float* __restrict__ bnp)
{
    int j = threadIdx.x;
    if (j >= HH) return;
    const float invn = 1.0f / (float)NN;
    float mu  = stats[j] * invn;
    float var = stats[32 + j] * invn - mu * mu;
    float rs  = 1.0f / sqrtf(var + 1e-5f);
    float sc  = rs * gamma[j];
    bnp[j]      = sc;
    bnp[32 + j] = beta[j] - mu * sc;
}

__global__ __launch_bounds__(256) void bn_apply(float* __restrict__ h,
                                                const float* __restrict__ bnp)
{
    int idx = blockIdx.x * 256 + threadIdx.x;
    if (idx >= NN * HH / 4) return;
    float4 v = ((float4*)h)[idx];
    int j = (idx * 4) & 31;
    v.x = fmaf(v.x, bnp[j + 0], bnp[32 + j + 0]);
    v.y = fmaf(v.y, bnp[j + 1], bnp[32 + j + 1]);
    v.z = fmaf(v.z, bnp[j + 2], bnp[32 + j + 2]);
    v.w = fmaf(v.w, bnp[j + 3], bnp[32 + j + 3]);
    ((float4*)h)[idx] = v;
}

// ---------------- CSR build: scan + scatter (dst order is layer-invariant) ----------
__global__ __launch_bounds__(256) void scan1(const int* __restrict__ degi,
                                             int* __restrict__ rowptr,
                                             int* __restrict__ bsum)
{
    __shared__ int sd[256];
    int tid = threadIdx.x;
    int i = blockIdx.x * 256 + tid;
    int v = (i < NN) ? degi[i] : 0;
    sd[tid] = v;
    __syncthreads();
    #pragma unroll
    for (int off = 1; off < 256; off <<= 1) {
        int t = (tid >= off) ? sd[tid - off] : 0;
        __syncthreads();
        sd[tid] += t;
        __syncthreads();
    }
    if (i < NN) rowptr[i] = sd[tid] - v;
    if (tid == 255) bsum[blockIdx.x] = sd[255];
}

__global__ __launch_bounds__(512) void scan2(int* __restrict__ bsum)
{
    __shared__ int sd[512];
    int tid = threadIdx.x;
    int v = (tid < 391) ? bsum[tid] : 0;
    sd[tid] = v;
    __syncthreads();
    #pragma unroll
    for (int off = 1; off < 512; off <<= 1) {
        int t = (tid >= off) ? sd[tid - off] : 0;
        __syncthreads();
        sd[tid] += t;
        __syncthreads();
    }
    if (tid < 391) bsum[tid] = sd[tid] - v;
}

__global__ __launch_bounds__(256) void scan3(int* __restrict__ rowptr,
                                             const int* __restrict__ bsum,
                                             int* __restrict__ cursor)
{
    int i = blockIdx.x * 256 + threadIdx.x;
    if (i < NN) {
        int r = rowptr[i] + bsum[blockIdx.x];
        rowptr[i] = r;
        cursor[i] = r;
    }
    if (i == 0) rowptr[NN] = NE;
}

__global__ __launch_bounds__(256) void scatter_k(const int* __restrict__ ei,
                                                 int* __restrict__ cursor,
                                                 int* __restrict__ perm)
{
    int e = blockIdx.x * 256 + threadIdx.x;
    if (e >= NE) return;
    int d = ei[NE + e];
    int pos = atomicAdd(&cursor[d], 1);
    perm[pos] = e;
}

// ---------------- NNConv edge kernel via MFMA; 8 waves x 32 edges ----------------
// CRITICAL: __launch_bounds__(512, 3). With the hint the allocator emits 64 VGPR =
// the 8-waves/SIMD hardware boundary (m69: waves halve at 64/128/256) -> 3 blk/CU,
// Occ ~29.6%, edge ~94us (R7 run). Without it: 68 VGPR -> wave cap halves ->
// Occ 17.4%, edge ~121us (R12/R13, deterministic). The R4 spill lesson applies only
// to the et=4 variant (needs ~160 VGPR); this et=2 kernel fits 64 naturally.
// Falsified alternates (do NOT reintroduce):
//  - et=4 + forced bounds: scratch spills (R4: 9x HBM traffic).
//  - B direct-from-global ping-pong: request-rate bound, 165us (R6).
//  - memory-gathered acc init (b2h): 128-VGPR spill cliff (R8/R9).
//  - double-buffered staging (64/32-col): LDS-DMA vs ds_read ordering serializes,
//    118-119us (R10/R11).
__global__ __launch_bounds__(512, 3) void edge_mfma(
    const float* __restrict__ h, const int* __restrict__ ei,
    const float* __restrict__ ea, const int* __restrict__ perm,
    const float* __restrict__ w1, const float* __restrict__ b1,
    const unsigned short* __restrict__ w2h, const unsigned short* __restrict__ w2l,
    const float* __restrict__ b2, float* __restrict__ msg)
{
    __shared__ float hT[32 * 256];              // 32 KB
    __shared__ float b2l[1024];                 // 4 KB
    __shared__ unsigned short Bh[4096];         // 8 KB: 64 n-rows x 64 k, swizzled
    __shared__ unsigned short Bl[4096];         // 8 KB   (total 53248 B)

    const int tid  = threadIdx.x;
    const int w    = tid >> 6;                  // 0..7
    const int lane = tid & 63;
    const int l15  = lane & 15;
    const int lg   = lane >> 4;                 // 0..3
    const int eb   = blockIdx.x * 256;
    const int wb32 = w * 32;                    // wave's edge sub-tile base

    const unsigned int* gh = (const unsigned int*)w2h;   // granule = 16 B
    const unsigned int* gl = (const unsigned int*)w2l;

    auto stage = [&](int c2) {
        int g = tid;                             // granule id 0..511
        int n = g >> 3, j = g & 7;
        int gi = ((c2 * 64 + n) << 3) + (j ^ (n & 7));
        int lb = (tid & ~63) * 8;                // shorts; wave-uniform base
        __builtin_amdgcn_global_load_lds(
            (const __attribute__((address_space(1))) unsigned int*)(gh + (size_t)gi * 4),
            (__attribute__((address_space(3))) unsigned int*)(&Bh[0] + lb), 16, 0, 0);
        __builtin_amdgcn_global_load_lds(
            (const __attribute__((address_space(1))) unsigned int*)(gl + (size_t)gi * 4),
            (__attribute__((address_space(3))) unsigned int*)(&Bl[0] + lb), 16, 0, 0);
    };

    // ---- stage per-block edge data (dst-sorted via perm); 2 threads per edge ----
    {
        int eloc = tid & 255;
        int half = tid >> 8;                     // 0 or 1 -> columns 0-15 / 16-31
        int e = eb + eloc;
        int pe = (e < NE) ? perm[e] : 0;
        int s  = (e < NE) ? ei[pe] : 0;
        const float4* hp = (const float4*)(h + (size_t)s * HH) + half * 4;
        #pragma unroll
        for (int q = 0; q < 4; ++q) {
            float4 v = hp[q];
            int col = half * 16 + q * 4;
            hT[(col + 0) * 256 + eloc] = v.x;
            hT[(col + 1) * 256 + eloc] = v.y;
            hT[(col + 2) * 256 + eloc] = v.z;
            hT[(col + 3) * 256 + eloc] = v.w;
        }
        if (tid < 256) ((float4*)b2l)[tid] = ((const float4*)b2)[tid];
    }

    // ---- A-operand fragments: T = relu(ea@w1+b1), split hi/lo bf16 (et = 0,1) ----
    bf16x8 thi[2][2], tlo[2][2];
    #pragma unroll
    for (int et = 0; et < 2; ++et) {
        int e2 = eb + wb32 + et * 16 + l15;
        bool ev = (e2 < NE);
        int pe2 = ev ? perm[e2] : 0;
        float4 eav = make_float4(0.f, 0.f, 0.f, 0.f);
        if (ev) eav = *(const float4*)(ea + (size_t)pe2 * 4);
        #pragma unroll
        for (int ks = 0; ks < 2; ++ks) {
            int k0 = ks * 32 + lg * 8;
            #pragma unroll
            for (int j = 0; j < 8; ++j) {
                float t = b1[k0 + j];
                t = fmaf(eav.x, w1[0 * 64 + k0 + j], t);
                t = fmaf(eav.y, w1[1 * 64 + k0 + j], t);
                t = fmaf(eav.z, w1[2 * 64 + k0 + j], t);
                t = fmaf(eav.w, w1[3 * 64 + k0 + j], t);
                t = ev ? fmaxf(t, 0.f) : 0.f;
                unsigned short hi = bf16_rne(t);
                float lov = t - bf16_f(hi);
                unsigned short lo = bf16_rne(lov);
                thi[et][ks][j] = (short)hi;
                tlo[et][ks][j] = (short)lo;
            }
        }
    }

    float acc0[2][4], acc1[2][4];
    #pragma unroll
    for (int et = 0; et < 2; ++et)
        #pragma unroll
        for (int r = 0; r < 4; ++r) { acc0[et][r] = 0.f; acc1[et][r] = 0.f; }

    // ---- main loop: 16 chunks of 64 n-cols, single LDS buffer ----
    for (int c2 = 0; c2 < 16; ++c2) {
        __syncthreads();                 // buffer reusable (covers hT staging at c2==0)
        stage(c2);
        __syncthreads();                 // vmcnt drained before barrier -> data visible

        #pragma unroll
        for (int ntp = 0; ntp < 2; ++ntp) {
            const int i = c2 * 2 + ntp;  // h row for this 32-col pair
            float4 h4[2];
            #pragma unroll
            for (int et = 0; et < 2; ++et)
                h4[et] = *(const float4*)&hT[i * 256 + wb32 + et * 16 + lg * 4];
            #pragma unroll
            for (int half = 0; half < 2; ++half) {
                int nt = ntp * 2 + half;           // 0..3 within chunk
                int nl = nt * 16 + l15;            // chunk-local n row
                int swz = (nl & 7) << 4;
                const char* bhrow = (const char*)&Bh[0] + nl * 128;
                const char* blrow = (const char*)&Bl[0] + nl * 128;
                bf16x8 Bh0 = *(const bf16x8*)(bhrow + (( 0 + lg * 16) ^ swz));
                bf16x8 Bl0 = *(const bf16x8*)(blrow + (( 0 + lg * 16) ^ swz));
                bf16x8 Bh1 = *(const bf16x8*)(bhrow + ((64 + lg * 16) ^ swz));
                bf16x8 Bl1 = *(const bf16x8*)(blrow + ((64 + lg * 16) ^ swz));
                float b2v = b2l[c2 * 64 + nt * 16 + l15];
                #pragma unroll
                for (int et = 0; et < 2; ++et) {
                    f32x4 G = {0.f, 0.f, 0.f, 0.f};
                    G = __builtin_amdgcn_mfma_f32_16x16x32_bf16(thi[et][0], Bh0, G, 0, 0, 0);
                    G = __builtin_amdgcn_mfma_f32_16x16x32_bf16(tlo[et][0], Bh0, G, 0, 0, 0);
                    G = __builtin_amdgcn_mfma_f32_16x16x32_bf16(thi[et][0], Bl0, G, 0, 0, 0);
                    G = __builtin_amdgcn_mfma_f32_16x16x32_bf16(thi[et][1], Bh1, G, 0, 0, 0);
                    G = __builtin_amdgcn_mfma_f32_16x16x32_bf16(tlo[et][1], Bh1, G, 0, 0, 0);
                    G = __builtin_amdgcn_mfma_f32_16x16x32_bf16(thi[et][1], Bl1, G, 0, 0, 0);
                    if (half == 0) {
                        acc0[et][0] = fmaf(h4[et].x, G[0] + b2v, acc0[et][0]);
                        acc0[et][1] = fmaf(h4[et].y, G[1] + b2v, acc0[et][1]);
                        acc0[et][2] = fmaf(h4[et].z, G[2] + b2v, acc0[et][2]);
                        acc0[et][3] = fmaf(h4[et].w, G[3] + b2v, acc0[et][3]);
                    } else {
                        acc1[et][0] = fmaf(h4[et].x, G[0] + b2v, acc1[et][0]);
                        acc1[et][1] = fmaf(h4[et].y, G[1] + b2v, acc1[et][1]);
                        acc1[et][2] = fmaf(h4[et].z, G[2] + b2v, acc1[et][2]);
                        acc1[et][3] = fmaf(h4[et].w, G[3] + b2v, acc1[et][3]);
                    }
                }
            }
        }
    }

    // ---- plain coalesced stores (msg indexed by sorted position) ----
    #pragma unroll
    for (int et = 0; et < 2; ++et) {
        #pragma unroll
        for (int r = 0; r < 4; ++r) {
            int row = eb + wb32 + et * 16 + lg * 4 + r;
            if (row < NE) {
                msg[(size_t)row * HH + l15]      = acc0[et][r];
                msg[(size_t)row * HH + 16 + l15] = acc1[et][r];
            }
        }
    }
}

// ---------------- node update: CSR gather (no atomics) ----------------
__global__ __launch_bounds__(256) void node_kernel(
    const float* __restrict__ h, const float* __restrict__ msg,
    const int* __restrict__ rowptr, const float* __restrict__ root,
    const float* __restrict__ bias, float* __restrict__ hout)
{
    int nid = blockIdx.x * 256 + threadIdx.x;
    if (nid >= NN) return;
    int j0 = rowptr[nid], j1 = rowptr[nid + 1];
    float hv[HH];
    {
        const float4* hp = (const float4*)(h + (size_t)nid * HH);
        #pragma unroll
        for (int q = 0; q < 8; ++q) {
            float4 v = hp[q];
            hv[4*q+0] = v.x; hv[4*q+1] = v.y; hv[4*q+2] = v.z; hv[4*q+3] = v.w;
        }
    }
    float acc[HH];
    #pragma unroll
    for (int o = 0; o < HH; ++o) acc[o] = bias[o];
    #pragma unroll
    for (int i = 0; i < HH; ++i) {
        float hi = hv[i];
        #pragma unroll
        for (int o = 0; o < HH; ++o) acc[o] = fmaf(hi, root[i * HH + o], acc[o]);
    }
    float s[HH];
    #pragma unroll
    for (int o = 0; o < HH; ++o) s[o] = 0.f;
    for (int j = j0; j < j1; ++j) {
        const float4* mp = (const float4*)(msg + (size_t)j * HH);
        #pragma unroll
        for (int q = 0; q < 8; ++q) {
            float4 m = mp[q];
            s[4*q+0] += m.x; s[4*q+1] += m.y; s[4*q+2] += m.z; s[4*q+3] += m.w;
        }
    }
    float inv = 1.0f / fmaxf((float)(j1 - j0), 1.0f);
    float4* op = (float4*)(hout + (size_t)nid * HH);
    #pragma unroll
    for (int q = 0; q < 8; ++q) {
        float4 r;
        r.x = fmaxf(fmaf(s[4*q+0], inv, acc[4*q+0]), 0.f);
        r.y = fmaxf(fmaf(s[4*q+1], inv, acc[4*q+1]), 0.f);
        r.z = fmaxf(fmaf(s[4*q+2], inv, acc[4*q+2]), 0.f);
        r.w = fmaxf(fmaf(s[4*q+3], inv, acc[4*q+3]), 0.f);
        op[q] = r;
    }
}

// ---------------- global mean pool (sorted batch -> run accumulation) ----------------
__global__ __launch_bounds__(256) void pool_kernel(
    const float* __restrict__ h, const int* __restrict__ batch,
    float* __restrict__ pool, float* __restrict__ cnt)
{
    __shared__ float lp[NGR * HH];
    __shared__ float lc[NGR];
    int tid = threadIdx.x;
    for (int i = tid; i < NGR * HH; i += 256) lp[i] = 0.f;
    if (tid < NGR) lc[tid] = 0.f;
    __syncthreads();
    int c = tid & 31, grp = tid >> 5;           // 8 groups x 32 cols
    int base = blockIdx.x * 1024 + grp * 128;
    int curg = -1;
    float acc = 0.f, cn = 0.f;
    for (int s = 0; s < 128; ++s) {
        int n = base + s;
        if (n >= NN) break;
        int g = batch[n];
        if (g != curg) {
            if (curg >= 0) {
                atomicAdd(&lp[curg * HH + c], acc);
                if (c == 0) atomicAdd(&lc[curg], cn);
            }
            curg = g; acc = 0.f; cn = 0.f;
        }
        acc += h[(size_t)n * HH + c];
        cn += 1.f;
    }
    if (curg >= 0) {
        atomicAdd(&lp[curg * HH + c], acc);
        if (c == 0) atomicAdd(&lc[curg], cn);
    }
    __syncthreads();
    for (int i = tid; i < NGR * HH; i += 256)
        if (lp[i] != 0.f) unsafeAtomicAdd(&pool[i], lp[i]);
    if (tid < NGR && lc[tid] != 0.f) unsafeAtomicAdd(&cnt[tid], lc[tid]);
}

// ---------------- heads ----------------
__global__ __launch_bounds__(256) void heads_kernel(
    const float* __restrict__ pool, const float* __restrict__ cnt,
    const float* __restrict__ wkw1, const float* __restrict__ wkb1,
    const float* __restrict__ wkw2, const float* __restrict__ wkb2,
    const float* __restrict__ ujw1, const float* __restrict__ ujb1,
    const float* __restrict__ ujw2, const float* __restrict__ ujb2,
    const float* __restrict__ zkw1, const float* __restrict__ zkb1,
    const float* __restrict__ zkw2, const float* __restrict__ zkb2,
    float* __restrict__ out)
{
    __shared__ float hg[NGR * HH];
    __shared__ float hid[NGR * HH];
    int tid = threadIdx.x;
    int head = blockIdx.x;
    const float *w1, *b1, *w2, *b2;
    if (head == 0)      { w1 = wkw1; b1 = wkb1; w2 = wkw2; b2 = wkb2; }
    else if (head == 1) { w1 = ujw1; b1 = ujb1; w2 = ujw2; b2 = ujb2; }
    else                { w1 = zkw1; b1 = zkb1; w2 = zkw2; b2 = zkb2; }
    for (int i = tid; i < NGR * HH; i += 256) {
        int g = i >> 5;
        hg[i] = pool[i] / fmaxf(cnt[g], 1.0f);
    }
    __syncthreads();
    for (int i = tid; i < NGR * HH; i += 256) {
        int g = i >> 5, c = i & 31;
        float a = b1[c];
        for (int j = 0; j < HH; ++j) a = fmaf(hg[g * HH + j], w1[j * HH + c], a);
        hid[i] = fmaxf(a, 0.f);
    }
    __syncthreads();
    if (head == 0) {
        if (tid < NGR) {
            float a = b2[0];
            for (int c = 0; c < HH; ++c) a = fmaf(hid[tid * HH + c], w2[c], a);
            out[tid] = a;
        }
    } else {
        float* ob = out + NGR + (head - 1) * NGR * GOUT;
        for (int i = tid; i < NGR * GOUT; i += 256) {
            int g = i / GOUT, u = i % GOUT;
            float a = b2[u];
            for (int c = 0; c < HH; ++c) a = fmaf(hid[g * HH + c], w2[c * GOUT + u], a);
            ob[i] = a;
        }
    }
}

extern "C" void kernel_launch(void* const* d_in, const int* in_sizes, int n_in,
                              void* d_out, int out_size, void* d_ws, size_t ws_size,
                              hipStream_t stream)
{
    const float* x     = (const float*)d_in[0];
    const int*   ei    = (const int*)d_in[1];
    const float* ea    = (const float*)d_in[2];
    const int*   batch = (const int*)d_in[3];
    const float* w_emb = (const float*)d_in[4];
    const float* b_emb = (const float*)d_in[5];
    const float* gamma = (const float*)d_in[6];
    const float* beta  = (const float*)d_in[7];
    const float* cw1   = (const float*)d_in[8];
    const float* cb1   = (const float*)d_in[9];
    const float* cw2   = (const float*)d_in[10];
    const float* cb2   = (const float*)d_in[11];
    const float* croot = (const float*)d_in[12];
    const float* cbias = (const float*)d_in[13];
    float* out = (float*)d_out;

    // ---- ws layout (16B-aligned chunks) ----
    unsigned short* w2h = (unsigned short*)d_ws;           // 512 KB
    unsigned short* w2l = w2h + 262144;                    // 512 KB
    float* msg    = (float*)(w2l + 262144);                // 25.6 MB
    float* h0     = msg + (size_t)NE * HH;                 // 12.8 MB
    float* h1     = h0 + (size_t)NN * HH;                  // 12.8 MB
    int*   rowptr = (int*)(h1 + (size_t)NN * HH);          // 100004
    int*   cursor = rowptr + 100004;                       // NN
    int*   perm   = cursor + NN;                           // NE
    int*   degi   = perm + NE;                             // NN   <- zero from here
    int*   bsum   = degi + NN;                             // 512
    float* stats  = (float*)(bsum + 512);                  // 64
    float* pool   = stats + 64;                            // 1600
    float* cnt    = pool + NGR * HH;                       // 50
    float* bnp    = cnt + NGR;                             // 64

    hipMemsetAsync(degi, 0, (size_t)(NN + 512 + 64 + NGR * HH + NGR) * sizeof(int), stream);

    split_w2<<<(NL * 65536) / 256, 256, 0, stream>>>(cw2, w2h, w2l);
    embed_kernel<<<(NN + 255) / 256, 256, 0, stream>>>(x, w_emb, b_emb, h0);
    stats_kernel<<<128, 256, 0, stream>>>(h0, stats);
    degi_kernel<<<NEB, 256, 0, stream>>>(ei, degi);
    bn_finalize<<<1, 32, 0, stream>>>(stats, gamma, beta, bnp);
    bn_apply<<<(NN * HH / 4 + 255) / 256, 256, 0, stream>>>(h0, bnp);

    // CSR build (dst order is layer-invariant)
    scan1<<<391, 256, 0, stream>>>(degi, rowptr, bsum);
    scan2<<<1, 512, 0, stream>>>(bsum);
    scan3<<<391, 256, 0, stream>>>(rowptr, bsum, cursor);
    scatter_k<<<NEB, 256, 0, stream>>>(ei, cursor, perm);

    float* hc = h0;
    float* hn = h1;
    for (int l = 0; l < NL; ++l) {
        edge_mfma<<<NEB, 512, 0, stream>>>(
            hc, ei, ea, perm,
            cw1 + (size_t)l * 4 * 64, cb1 + (size_t)l * 64,
            w2h + (size_t)l * 65536, w2l + (size_t)l * 65536,
            cb2 + (size_t)l * 1024, msg);
        node_kernel<<<(NN + 255) / 256, 256, 0, stream>>>(
            hc, msg, rowptr, croot + (size_t)l * HH * HH, cbias + (size_t)l * HH, hn);
        float* t = hc; hc = hn; hn = t;
    }

    pool_kernel<<<(NN + 1023) / 1024, 256, 0, stream>>>(hc, batch, pool, cnt);
    heads_kernel<<<3, 256, 0, stream>>>(pool, cnt,
        (const float*)d_in[14], (const float*)d_in[15], (const float*)d_in[16], (const float*)d_in[17],
        (const float*)d_in[18], (const float*)d_in[19], (const float*)d_in[20], (const float*)d_in[21],
        (const float*)d_in[22], (const float*)d_in[23], (const float*)d_in[24], (const float*)d_in[25],
        out);
}